// Round 1
// baseline (363.470 us; speedup 1.0000x reference)
//
#include <hip/hip_runtime.h>
#include <math.h>

#define B 64
#define P 16800
#define O 64
#define NCHUNK 66          // ceil(16800/256)
#define THRESH 0.35f
#define VALID_T 0.2f

__device__ __forceinline__ float smooth_l1(float x) {
    float ax = fabsf(x);
    return ax < 1.f ? 0.5f * ax * ax : ax - 0.5f;
}

// ---------------- Kernel A: per-prior best truth (argmax over O, first-max tie-break)
__global__ void kA_best_truth(const float* __restrict__ priors,
                              const float* __restrict__ targets,
                              float* __restrict__ bt_ov, int* __restrict__ bt_idx) {
    int chunk = blockIdx.x % NCHUNK;
    int b = blockIdx.x / NCHUNK;
    __shared__ float tg[O * 15];
    for (int i = threadIdx.x; i < O * 15; i += blockDim.x) tg[i] = targets[b * O * 15 + i];
    __syncthreads();
    int p = chunk * 256 + threadIdx.x;
    if (p >= P) return;
    float cx = priors[p * 4 + 0], cy = priors[p * 4 + 1];
    float sw = priors[p * 4 + 2], sh = priors[p * 4 + 3];
    float px1 = cx - sw * 0.5f, py1 = cy - sh * 0.5f;
    float px2 = cx + sw * 0.5f, py2 = cy + sh * 0.5f;
    float area_b = (px2 - px1) * (py2 - py1);
    float best = -1.f; int bi = 0;
    for (int o = 0; o < O; ++o) {
        const float* t = &tg[o * 15];
        float w = fmaxf(fminf(t[2], px2) - fmaxf(t[0], px1), 0.f);
        float h = fmaxf(fminf(t[3], py2) - fmaxf(t[1], py1), 0.f);
        float inter = w * h;
        float area_a = (t[2] - t[0]) * (t[3] - t[1]);
        float iou = inter / (area_a + area_b - inter);
        if (iou > best) { best = iou; bi = o; }   // strict >: first max wins (jnp.argmax)
    }
    bt_ov[b * P + p] = best;
    bt_idx[b * P + p] = bi;
}

// ---------------- Kernel B: per-truth best prior (argmax over P, smallest-p tie-break)
__global__ void kB_best_prior(const float* __restrict__ priors,
                              const float* __restrict__ targets,
                              int* __restrict__ bp_idx, int* __restrict__ bp_valid) {
    int o = blockIdx.x % O;
    int b = blockIdx.x / O;
    const float* t = &targets[(b * O + o) * 15];
    float tx1 = t[0], ty1 = t[1], tx2 = t[2], ty2 = t[3];
    float area_a = (tx2 - tx1) * (ty2 - ty1);
    unsigned long long best = 0ULL;
    for (int p = threadIdx.x; p < P; p += blockDim.x) {
        float cx = priors[p * 4 + 0], cy = priors[p * 4 + 1];
        float sw = priors[p * 4 + 2], sh = priors[p * 4 + 3];
        float px1 = cx - sw * 0.5f, py1 = cy - sh * 0.5f;
        float px2 = cx + sw * 0.5f, py2 = cy + sh * 0.5f;
        float area_b = (px2 - px1) * (py2 - py1);
        float w = fmaxf(fminf(tx2, px2) - fmaxf(tx1, px1), 0.f);
        float h = fmaxf(fminf(ty2, py2) - fmaxf(ty1, py1), 0.f);
        float inter = w * h;
        float iou = inter / (area_a + area_b - inter);
        // pack: higher iou wins; equal iou -> smaller p wins
        unsigned long long key =
            ((unsigned long long)__float_as_uint(iou) << 32) | (unsigned)(0xFFFFFFFFu - (unsigned)p);
        if (key > best) best = key;
    }
    __shared__ unsigned long long red[256];
    red[threadIdx.x] = best;
    __syncthreads();
    for (int s = 128; s > 0; s >>= 1) {
        if (threadIdx.x < s) {
            unsigned long long a = red[threadIdx.x], c = red[threadIdx.x + s];
            red[threadIdx.x] = a > c ? a : c;
        }
        __syncthreads();
    }
    if (threadIdx.x == 0) {
        unsigned long long k = red[0];
        int p = (int)(0xFFFFFFFFu - (unsigned)(k & 0xFFFFFFFFu));
        float iou = __uint_as_float((unsigned)(k >> 32));
        bp_idx[b * O + o] = p;
        bp_valid[b * O + o] = (iou >= VALID_T) ? 1 : 0;
    }
}

// ---------------- Kernel C: scatter overrides (serial per row; numpy last-write-wins,
// scattered bt_ov values read from PRE-scatter array)
__global__ void kC_scatter(const int* __restrict__ bp_idx, const int* __restrict__ bp_valid,
                           float* __restrict__ bt_ov, int* __restrict__ bt_idx,
                           int* __restrict__ any_valid) {
    int b = blockIdx.x;
    if (threadIdx.x != 0) return;
    float orig[O];
    for (int j = 0; j < O; ++j) orig[j] = bt_ov[b * P + bp_idx[b * O + j]]; // read all before writes
    int av = 0;
    for (int j = 0; j < O; ++j) {
        int p = bp_idx[b * O + j];
        int v = bp_valid[b * O + j];
        av |= v;
        bt_ov[b * P + p] = v ? 2.0f : orig[j];
        bt_idx[b * P + p] = j;   // unconditional, even for invalid truths
    }
    any_valid[b] = av;
}

// ---------------- Kernel D: per-prior losses + CE + rank score
__global__ void kD_main(const float* __restrict__ loc_data, const float* __restrict__ conf_data,
                        const float* __restrict__ landm_data, const float* __restrict__ priors,
                        const float* __restrict__ targets,
                        const float* __restrict__ bt_ov, const int* __restrict__ bt_idx,
                        const int* __restrict__ any_valid,
                        float* __restrict__ rank,
                        int* __restrict__ num_pos, float* __restrict__ pos_ce,
                        float* __restrict__ gsum, int* __restrict__ num_pos1_tot) {
    int chunk = blockIdx.x % NCHUNK;
    int b = blockIdx.x / NCHUNK;
    __shared__ float tg[O * 15];
    __shared__ float sredf[256];
    __shared__ int sredi[256];
    for (int i = threadIdx.x; i < O * 15; i += blockDim.x) tg[i] = targets[b * O * 15 + i];
    __syncthreads();
    int p = chunk * 256 + threadIdx.x;
    float ll = 0.f, llm = 0.f, cep = 0.f;
    int cp = 0, cp1 = 0;
    if (p < P) {
        float ov = bt_ov[b * P + p];
        int ti = bt_idx[b * P + p];
        int conf = 0;
        if (any_valid[b] && ov >= THRESH) conf = (int)tg[ti * 15 + 14];   // label is +-1.0 exactly
        float c0 = conf_data[(b * P + p) * 2 + 0];
        float c1 = conf_data[(b * P + p) * 2 + 1];
        float m = fmaxf(c0, c1);
        float lse = m + logf(expf(c0 - m) + expf(c1 - m));
        bool pos = conf != 0;
        float ce = lse - (pos ? c1 : c0);
        rank[b * P + p] = pos ? 0.f : ce;
        if (pos) {
            cp = 1; cep = ce;
            float cx = priors[p * 4 + 0], cy = priors[p * 4 + 1];
            float sw = priors[p * 4 + 2], sh = priors[p * 4 + 3];
            const float* t = &tg[ti * 15];
            float gx = ((t[0] + t[2]) * 0.5f - cx) / (0.1f * sw);
            float gy = ((t[1] + t[3]) * 0.5f - cy) / (0.1f * sh);
            float gw = logf((t[2] - t[0]) / sw) / 0.2f;
            float gh = logf((t[3] - t[1]) / sh) / 0.2f;
            const float* ld = &loc_data[(size_t)(b * P + p) * 4];
            ll = smooth_l1(ld[0] - gx) + smooth_l1(ld[1] - gy) +
                 smooth_l1(ld[2] - gw) + smooth_l1(ld[3] - gh);
            if (conf > 0) {
                cp1 = 1;
                const float* lmd = &landm_data[(size_t)(b * P + p) * 10];
                for (int k5 = 0; k5 < 5; ++k5) {
                    float lx = (t[4 + k5 * 2 + 0] - cx) / (0.1f * sw);
                    float ly = (t[4 + k5 * 2 + 1] - cy) / (0.1f * sh);
                    llm += smooth_l1(lmd[k5 * 2 + 0] - lx) + smooth_l1(lmd[k5 * 2 + 1] - ly);
                }
            }
        }
    }
    // block reductions (all threads participate)
    sredf[threadIdx.x] = ll; __syncthreads();
    for (int s = 128; s > 0; s >>= 1) { if (threadIdx.x < s) sredf[threadIdx.x] += sredf[threadIdx.x + s]; __syncthreads(); }
    float ll_t = sredf[0]; __syncthreads();
    sredf[threadIdx.x] = llm; __syncthreads();
    for (int s = 128; s > 0; s >>= 1) { if (threadIdx.x < s) sredf[threadIdx.x] += sredf[threadIdx.x + s]; __syncthreads(); }
    float llm_t = sredf[0]; __syncthreads();
    sredf[threadIdx.x] = cep; __syncthreads();
    for (int s = 128; s > 0; s >>= 1) { if (threadIdx.x < s) sredf[threadIdx.x] += sredf[threadIdx.x + s]; __syncthreads(); }
    float cep_t = sredf[0]; __syncthreads();
    sredi[threadIdx.x] = cp; __syncthreads();
    for (int s = 128; s > 0; s >>= 1) { if (threadIdx.x < s) sredi[threadIdx.x] += sredi[threadIdx.x + s]; __syncthreads(); }
    int cp_t = sredi[0]; __syncthreads();
    sredi[threadIdx.x] = cp1; __syncthreads();
    for (int s = 128; s > 0; s >>= 1) { if (threadIdx.x < s) sredi[threadIdx.x] += sredi[threadIdx.x + s]; __syncthreads(); }
    int cp1_t = sredi[0];
    if (threadIdx.x == 0) {
        if (ll_t != 0.f)  atomicAdd(&gsum[0], ll_t);
        if (llm_t != 0.f) atomicAdd(&gsum[1], llm_t);
        if (cep_t != 0.f) atomicAdd(&pos_ce[b], cep_t);
        if (cp_t)  atomicAdd(&num_pos[b], cp_t);
        if (cp1_t) atomicAdd(num_pos1_tot, cp1_t);
    }
}

// ---------------- Kernel E: per-row sum of top-k rank scores via radix select
__global__ void kE_topk(const float* __restrict__ rank, const int* __restrict__ num_pos,
                        float* __restrict__ topk) {
    int b = blockIdx.x;
    const float* r = rank + (size_t)b * P;
    int k = num_pos[b] * 7;
    if (k > P - 1) k = P - 1;
    if (k <= 0) { if (threadIdx.x == 0) topk[b] = 0.f; return; }
    __shared__ int hist[256];
    __shared__ int s_bin, s_kk;
    __shared__ float sredf[256];
    __shared__ int sredi[256];
    unsigned prefix = 0u;
    int kk = k;
    for (int pass = 0; pass < 4; ++pass) {
        int shift = 24 - pass * 8;
        for (int i = threadIdx.x; i < 256; i += blockDim.x) hist[i] = 0;
        __syncthreads();
        unsigned mask = (pass == 0) ? 0u : (0xFFFFFFFFu << (32 - pass * 8));
        for (int p = threadIdx.x; p < P; p += blockDim.x) {
            unsigned u = __float_as_uint(r[p]);   // all values >= 0 -> bits monotone
            if ((u & mask) == prefix) atomicAdd(&hist[(u >> shift) & 0xFF], 1);
        }
        __syncthreads();
        if (threadIdx.x == 0) {
            int cum = 0, bin = 0, kn = kk;
            for (int i = 255; i >= 0; --i) {
                if (cum + hist[i] >= kk) { bin = i; kn = kk - cum; break; }
                cum += hist[i];
            }
            s_bin = bin; s_kk = kn;
        }
        __syncthreads();
        prefix |= ((unsigned)s_bin) << shift;
        kk = s_kk;
    }
    float t = __uint_as_float(prefix);   // exact k-th largest value
    float sum = 0.f; int cnt = 0;
    for (int p = threadIdx.x; p < P; p += blockDim.x) {
        float v = r[p];
        if (v > t) { sum += v; cnt++; }
    }
    sredf[threadIdx.x] = sum; sredi[threadIdx.x] = cnt; __syncthreads();
    for (int s = 128; s > 0; s >>= 1) {
        if (threadIdx.x < s) { sredf[threadIdx.x] += sredf[threadIdx.x + s]; sredi[threadIdx.x] += sredi[threadIdx.x + s]; }
        __syncthreads();
    }
    if (threadIdx.x == 0) topk[b] = sredf[0] + (float)(k - sredi[0]) * t;
}

// ---------------- Kernel F: finalize
__global__ void kF_final(const int* __restrict__ num_pos, const float* __restrict__ pos_ce,
                         const float* __restrict__ topk, const float* __restrict__ gsum,
                         const int* __restrict__ num_pos1_tot, float* __restrict__ out) {
    if (threadIdx.x != 0 || blockIdx.x != 0) return;
    int np = 0; float lc = 0.f;
    for (int b = 0; b < B; ++b) { np += num_pos[b]; lc += pos_ce[b] + topk[b]; }
    float N = fmaxf((float)np, 1.f);
    float N1 = fmaxf((float)(*num_pos1_tot), 1.f);
    out[0] = gsum[0] / N;
    out[1] = lc / N;
    out[2] = gsum[1] / N1;
}

extern "C" void kernel_launch(void* const* d_in, const int* in_sizes, int n_in,
                              void* d_out, int out_size, void* d_ws, size_t ws_size,
                              hipStream_t stream) {
    const float* loc_data   = (const float*)d_in[0];
    const float* conf_data  = (const float*)d_in[1];
    const float* landm_data = (const float*)d_in[2];
    const float* priors     = (const float*)d_in[3];
    const float* targets    = (const float*)d_in[4];
    float* out = (float*)d_out;

    char* ws = (char*)d_ws;
    size_t off = 0;
    auto alloc = [&](size_t bytes) -> void* {
        void* p = ws + off;
        off += (bytes + 255) & ~(size_t)255;
        return p;
    };
    float* bt_ov    = (float*)alloc((size_t)B * P * 4);
    int*   bt_idx   = (int*)  alloc((size_t)B * P * 4);
    float* rank     = (float*)alloc((size_t)B * P * 4);
    int*   bp_idx   = (int*)  alloc(B * O * 4);
    int*   bp_valid = (int*)  alloc(B * O * 4);
    // accumulator block (zeroed each launch): any_valid[B], num_pos[B], pos_ce[B], topk[B], gsum[2], np1[1]
    size_t acc_bytes = (size_t)(B * 4 * 4 + 16);
    char* acc = (char*)alloc(acc_bytes);
    int*   any_valid    = (int*)acc;
    int*   num_pos      = (int*)(acc + B * 4);
    float* pos_ce       = (float*)(acc + 2 * B * 4);
    float* topk         = (float*)(acc + 3 * B * 4);
    float* gsum         = (float*)(acc + 4 * B * 4);
    int*   num_pos1_tot = (int*)(acc + 4 * B * 4 + 8);

    hipMemsetAsync(acc, 0, acc_bytes, stream);

    kA_best_truth<<<dim3(B * NCHUNK), dim3(256), 0, stream>>>(priors, targets, bt_ov, bt_idx);
    kB_best_prior<<<dim3(B * O), dim3(256), 0, stream>>>(priors, targets, bp_idx, bp_valid);
    kC_scatter<<<dim3(B), dim3(64), 0, stream>>>(bp_idx, bp_valid, bt_ov, bt_idx, any_valid);
    kD_main<<<dim3(B * NCHUNK), dim3(256), 0, stream>>>(loc_data, conf_data, landm_data, priors,
                                                        targets, bt_ov, bt_idx, any_valid, rank,
                                                        num_pos, pos_ce, gsum, num_pos1_tot);
    kE_topk<<<dim3(B), dim3(256), 0, stream>>>(rank, num_pos, topk);
    kF_final<<<dim3(1), dim3(64), 0, stream>>>(num_pos, pos_ce, topk, gsum, num_pos1_tot, out);
}